// Round 5
// baseline (393.095 us; speedup 1.0000x reference)
//
#include <hip/hip_runtime.h>

typedef unsigned short u16;
typedef __attribute__((ext_vector_type(8))) __bf16 bf16x8;
typedef __attribute__((ext_vector_type(4))) float floatx4;

#define DDIM 2048
#define MROWS 16384   // 4*4096

__device__ __forceinline__ u16 f2bf(float f) {
    unsigned int u = __builtin_bit_cast(unsigned int, f);
    u = (u + 0x7fffu + ((u >> 16) & 1u)) >> 16;   // RNE
    return (u16)u;
}

__device__ __forceinline__ float wave_sum(float v) {
#pragma unroll
    for (int o = 32; o > 0; o >>= 1) v += __shfl_down(v, o, 64);
    return v;
}
__device__ __forceinline__ float wave_max(float v) {
#pragma unroll
    for (int o = 32; o > 0; o >>= 1) v = fmaxf(v, __shfl_down(v, o, 64));
    return v;
}

// ---------------- partial sums of |W| ----------------
__global__ __launch_bounds__(256) void absmean_part(const float4* __restrict__ W4,
                                                    float* __restrict__ partial) {
    float s = 0.f;
    for (int i = blockIdx.x * 256 + threadIdx.x; i < (DDIM * DDIM / 4); i += 1024 * 256) {
        float4 v = W4[i];
        s += fabsf(v.x) + fabsf(v.y) + fabsf(v.z) + fabsf(v.w);
    }
    s = wave_sum(s);
    __shared__ float red[4];
    if ((threadIdx.x & 63) == 0) red[threadIdx.x >> 6] = s;
    __syncthreads();
    if (threadIdx.x == 0) partial[blockIdx.x] = red[0] + red[1] + red[2] + red[3];
}

// ---------------- column FWHT (length 2048 over the ROW index) ----------------
// Block b owns 8 consecutive columns [8b, 8b+8) of the 2048x2048 input.
// LDS slab S[2048][9] f32 (pitch 9 breaks power-of-2 bank aliasing), 73728 B.
// QUANT: fuse w_scale finalize + ternary quantization (stage 1, reads W).
// BF16OUT: pack output to bf16 (stage 2, writes w3).
#define CFP 9   // LDS pitch in floats

template <bool QUANT, bool BF16OUT>
__global__ __launch_bounds__(256) void colfwht(const float* __restrict__ in,
                                               void* __restrict__ out,
                                               const float* __restrict__ partial) {
    extern __shared__ float S[];   // [2048][CFP]
    const int t = threadIdx.x;
    const int c8 = blockIdx.x * 8;

    float wsc = 0.f, half_t = 0.f;
    if (QUANT) {
        __shared__ float wred[4];
        float s = partial[t] + partial[t + 256] + partial[t + 512] + partial[t + 768];
        s = wave_sum(s);
        if ((t & 63) == 0) wred[t >> 6] = s;
        __syncthreads();
        float m = (wred[0] + wred[1] + wred[2] + wred[3]) * (1.0f / (float)(DDIM * DDIM));
        wsc = fmaxf(m, 1e-6f);
        half_t = 0.5f * wsc;
    }

    // load (+quant): 4096 float4 per block; k = i*256+t; row = k>>1; half = k&1
#pragma unroll
    for (int i = 0; i < 16; ++i) {
        const int k = i * 256 + t;
        const int row = k >> 1, half = k & 1;
        float4 v = *(const float4*)(in + (size_t)row * DDIM + c8 + half * 4);
        if (QUANT) {
            v.x = (v.x > half_t ? wsc : 0.f) + (v.x < -half_t ? -wsc : 0.f);
            v.y = (v.y > half_t ? wsc : 0.f) + (v.y < -half_t ? -wsc : 0.f);
            v.z = (v.z > half_t ? wsc : 0.f) + (v.z < -half_t ? -wsc : 0.f);
            v.w = (v.w > half_t ? wsc : 0.f) + (v.w < -half_t ? -wsc : 0.f);
        }
        float* sp = S + row * CFP + half * 4;
        sp[0] = v.x; sp[1] = v.y; sp[2] = v.z; sp[3] = v.w;
    }
    __syncthreads();

    // 5 radix-4 stages: h = 1<<(2s)
#pragma unroll
    for (int s = 0; s < 5; ++s) {
        const int h = 1 << (2 * s);
#pragma unroll
        for (int i = 0; i < 16; ++i) {
            const int task = i * 256 + t;          // 4096 tasks = 512 quads x 8 cols
            const int p = task >> 3, c = task & 7;
            const int i0 = ((p >> (2 * s)) << (2 * s + 2)) | (p & (h - 1));
            float* a0 = S + (size_t)i0 * CFP + c;
            const float x0 = a0[0];
            const float x1 = a0[(size_t)h * CFP];
            const float x2 = a0[(size_t)2 * h * CFP];
            const float x3 = a0[(size_t)3 * h * CFP];
            const float s01 = x0 + x1, d01 = x0 - x1;
            const float s23 = x2 + x3, d23 = x2 - x3;
            a0[0]                   = s01 + s23;
            a0[(size_t)h * CFP]     = d01 + d23;
            a0[(size_t)2 * h * CFP] = s01 - s23;
            a0[(size_t)3 * h * CFP] = d01 - d23;
        }
        __syncthreads();
    }
    // final radix-2 stage: h = 1024
#pragma unroll
    for (int i = 0; i < 32; ++i) {
        const int task = i * 256 + t;              // 8192 tasks = 1024 pairs x 8 cols
        const int p = task >> 3, c = task & 7;
        float* a0 = S + (size_t)p * CFP + c;
        const float x0 = a0[0];
        const float x1 = a0[(size_t)1024 * CFP];
        a0[0] = x0 + x1;
        a0[(size_t)1024 * CFP] = x0 - x1;
    }
    __syncthreads();

    // store: column c of S -> output ROW (c8+c), coalesced
    const int c = t >> 5, l = t & 31;
#pragma unroll
    for (int i = 0; i < 16; ++i) {
        const int o4 = i * 32 + l;
        const float r0 = S[(size_t)(o4 * 4 + 0) * CFP + c];
        const float r1 = S[(size_t)(o4 * 4 + 1) * CFP + c];
        const float r2 = S[(size_t)(o4 * 4 + 2) * CFP + c];
        const float r3 = S[(size_t)(o4 * 4 + 3) * CFP + c];
        if (BF16OUT) {
            uint2 v;
            v.x = (unsigned)f2bf(r0) | ((unsigned)f2bf(r1) << 16);
            v.y = (unsigned)f2bf(r2) | ((unsigned)f2bf(r3) << 16);
            ((uint2*)((u16*)out + (size_t)(c8 + c) * DDIM))[o4] = v;
        } else {
            ((float4*)((float*)out + (size_t)(c8 + c) * DDIM))[o4] =
                make_float4(r0, r1, r2, r3);
        }
    }
}

// ---------------- fused LayerNorm + int4 fake-quant -> bf16 ----------------
__global__ __launch_bounds__(256) void ln_quant(const float* __restrict__ X,
                                                const float* __restrict__ G,
                                                const float* __restrict__ Bt,
                                                u16* __restrict__ XQ) {
    const int row = blockIdx.x;
    const int t = threadIdx.x;
    const float4* rp = (const float4*)(X + (size_t)row * DDIM);
    float4 v0 = rp[t], v1 = rp[t + 256];
    float v[8] = {v0.x, v0.y, v0.z, v0.w, v1.x, v1.y, v1.z, v1.w};

    __shared__ float redA[4], redB[4], redC[4];
    const int wv = t >> 6, ln = t & 63;

    float s = 0.f, s2 = 0.f;
#pragma unroll
    for (int j = 0; j < 8; ++j) { s += v[j]; s2 += v[j] * v[j]; }
#pragma unroll
    for (int o = 32; o > 0; o >>= 1) {
        s += __shfl_down(s, o, 64);
        s2 += __shfl_down(s2, o, 64);
    }
    if (ln == 0) { redA[wv] = s; redB[wv] = s2; }
    __syncthreads();
    const float mu = (redA[0] + redA[1] + redA[2] + redA[3]) * (1.f / (float)DDIM);
    const float ex2 = (redB[0] + redB[1] + redB[2] + redB[3]) * (1.f / (float)DDIM);
    const float var = ex2 - mu * mu;
    const float rstd = rsqrtf(var + 1e-5f);

    const float4* gp = (const float4*)G;
    const float4* bp = (const float4*)Bt;
    float4 g0 = gp[t], g1 = gp[t + 256];
    float4 b0 = bp[t], b1 = bp[t + 256];
    float gg[8] = {g0.x, g0.y, g0.z, g0.w, g1.x, g1.y, g1.z, g1.w};
    float bb[8] = {b0.x, b0.y, b0.z, b0.w, b1.x, b1.y, b1.z, b1.w};

    float y[8];
    float am = 0.f;
#pragma unroll
    for (int j = 0; j < 8; ++j) {
        y[j] = (v[j] - mu) * rstd * gg[j] + bb[j];
        am = fmaxf(am, fabsf(y[j]));
    }
    float w = wave_max(am);
    if (ln == 0) redC[wv] = w;
    __syncthreads();
    const float scale = fmaxf(fmaxf(fmaxf(redC[0], redC[1]), fmaxf(redC[2], redC[3])), 1e-6f);

    const float r7 = 7.f / scale, s7 = scale / 7.f;
    unsigned int q[4];
#pragma unroll
    for (int j = 0; j < 8; j += 2) {
        float qa = fminf(fmaxf(rintf(y[j] * r7), -7.f), 7.f);
        float qb = fminf(fmaxf(rintf(y[j + 1] * r7), -7.f), 7.f);
        q[j >> 1] = (unsigned)f2bf(qa * s7) | ((unsigned)f2bf(qb * s7) << 16);
    }
    uint2 o0, o1;
    o0.x = q[0]; o0.y = q[1]; o1.x = q[2]; o1.y = q[3];
    uint2* orow = (uint2*)(XQ + (size_t)row * DDIM);
    orow[t] = o0;
    orow[t + 256] = o1;
}

// ---------------- GEMM: 256x256 tile, 8-phase, distributed staging ----------------
// Round-2 schedule (best measured: 117-121 us full-size). THIS ROUND: split into
// two M-halves (grid 256 = 1 block/CU, the m201-verified config) so the rocprof
// top-5 exposes the prep kernels' counters. moff = starting M row.
#define GBK 64
#define GNT (DDIM / GBK)      // 32 K-tiles
#define NITER (GNT / 2)       // 16 iterations
#define TILEU (256 * GBK)     // 16384 u16 per staged tile

__device__ __forceinline__ void gl_lds16(const u16* g, u16* l) {
    __builtin_amdgcn_global_load_lds((const __attribute__((address_space(1))) void*)g,
                                     (__attribute__((address_space(3))) void*)l,
                                     16, 0, 0);
}

#define PBAR do {                                                              \
    __builtin_amdgcn_sched_barrier(0);                                         \
    asm volatile("" ::: "memory");                                             \
    __builtin_amdgcn_s_barrier();                                              \
    asm volatile("" ::: "memory");                                             \
    __builtin_amdgcn_sched_barrier(0);                                         \
} while (0)

#define PWAIT8 do {                                                            \
    __builtin_amdgcn_sched_barrier(0);                                         \
    asm volatile("s_waitcnt vmcnt(8)" ::: "memory");                           \
    __builtin_amdgcn_s_barrier();                                              \
    asm volatile("" ::: "memory");                                             \
    __builtin_amdgcn_sched_barrier(0);                                         \
} while (0)

#define PWAIT0 do {                                                            \
    __builtin_amdgcn_sched_barrier(0);                                         \
    asm volatile("s_waitcnt vmcnt(0)" ::: "memory");                           \
    __builtin_amdgcn_s_barrier();                                              \
    asm volatile("" ::: "memory");                                             \
    __builtin_amdgcn_sched_barrier(0);                                         \
} while (0)

__global__ __launch_bounds__(512, 2) void gemm256(const u16* __restrict__ A,
                                                  const u16* __restrict__ B,
                                                  float* __restrict__ C,
                                                  int moff) {
    extern __shared__ __align__(16) u16 lds[];   // 4 * TILEU u16 = 128 KiB
    const int t = threadIdx.x;
    const int lane = t & 63;
    const int wid = t >> 6;
    const int wm = wid >> 2;   // 0..1
    const int wn = wid & 3;    // 0..3

    // block mapping: consecutive d share bn (B panel) per XCD; bijective for 256.
    const int d = blockIdx.x;
    const int bm = (d & 7) | ((d >> 6) << 3);   // 0..31
    const int bn = (d >> 3) & 7;                // 0..7

    const int l15 = lane & 15;
    const int kq = lane >> 4;
    const int x7 = lane & 7;
    const int c0 = (kq ^ x7) << 3;
    const int c1 = ((kq | 4) ^ x7) << 3;
    const int arow = (wm << 7) + l15;
    const int brow = (wn << 6) + l15;

    const int srow = t >> 3;
    const int gch = ((t & 7) ^ (srow & 7)) << 3;
    const u16* Ag = A + (size_t)(moff + bm * 256 + srow) * DDIM + gch;
    const u16* Bg = B + (size_t)(bn * 256 + srow) * DDIM + gch;
    u16* const AL0 = lds + t * 8;
    u16* const BL0 = lds + TILEU + t * 8;
    u16* const AL1 = lds + 2 * TILEU + t * 8;
    u16* const BL1 = lds + 3 * TILEU + t * 8;
    const u16* const Ab0 = lds;
    const u16* const Bb0 = lds + TILEU;
    const u16* const Ab1 = lds + 2 * TILEU;
    const u16* const Bb1 = lds + 3 * TILEU;

    floatx4 acc[8][4];
#pragma unroll
    for (int i = 0; i < 8; ++i)
#pragma unroll
        for (int j = 0; j < 4; ++j)
#pragma unroll
            for (int e = 0; e < 4; ++e) acc[i][j][e] = 0.f;

    bf16x8 a[4][2], b0v[2][2], b1v[2][2];

#define STGA(dst, q, ko) gl_lds16(Ag + (size_t)((q) * 64) * DDIM + (ko), (dst) + (q) * 4096)
#define STGB(dst, q, ko) gl_lds16(Bg + (size_t)((q) * 64) * DDIM + (ko), (dst) + (q) * 4096)

#define LDA(Ab, mh)                                                            \
    _Pragma("unroll") for (int fm = 0; fm < 4; ++fm) {                         \
        const u16* p = (Ab) + (arow + (mh) * 64 + fm * 16) * GBK;              \
        a[fm][0] = *(const bf16x8*)(p + c0);                                   \
        a[fm][1] = *(const bf16x8*)(p + c1);                                   \
    }

#define LDB(dst, Bb, nh)                                                       \
    _Pragma("unroll") for (int fn = 0; fn < 2; ++fn) {                         \
        const u16* p = (Bb) + (brow + (nh) * 32 + fn * 16) * GBK;              \
        dst[fn][0] = *(const bf16x8*)(p + c0);                                 \
        dst[fn][1] = *(const bf16x8*)(p + c1);                                 \
    }

#define MMA(mh, bsrc, nh)                                                      \
    __builtin_amdgcn_s_setprio(1);                                             \
    _Pragma("unroll") for (int fm = 0; fm < 4; ++fm)                           \
        _Pragma("unroll") for (int fn = 0; fn < 2; ++fn)                       \
            _Pragma("unroll") for (int ks = 0; ks < 2; ++ks)                   \
                acc[(mh) * 4 + fm][(nh) * 2 + fn] =                            \
                    __builtin_amdgcn_mfma_f32_16x16x32_bf16(                   \
                        a[fm][ks], bsrc[fn][ks],                               \
                        acc[(mh) * 4 + fm][(nh) * 2 + fn], 0, 0, 0);           \
    __builtin_amdgcn_s_setprio(0);

#pragma unroll
    for (int q = 0; q < 4; ++q) STGA(AL0, q, 0);
#pragma unroll
    for (int q = 0; q < 4; ++q) STGB(BL0, q, 0);
#pragma unroll
    for (int q = 0; q < 4; ++q) STGA(AL1, q, GBK);
#pragma unroll
    for (int q = 0; q < 4; ++q) STGB(BL1, q, GBK);
    PWAIT8;

    for (int it = 0; it < NITER; ++it) {
        const int kp0 = (it * 2 + 2) * GBK;
        const int kp1 = kp0 + GBK;
        const bool pf = (it < NITER - 1);

        // ---- K-tile 2it (buf0) ----
        LDA(Ab0, 0);
        LDB(b0v, Bb0, 0);
        PBAR;
        MMA(0, b0v, 0);
        LDB(b1v, Bb0, 1);
        if (pf) { STGA(AL0, 0, kp0); STGA(AL0, 2, kp0); }
        PBAR;
        MMA(0, b1v, 1);
        LDA(Ab0, 1);
        if (pf) { STGB(BL0, 0, kp0); STGB(BL0, 1, kp0); }
        PBAR;
        MMA(1, b0v, 0);
        if (pf) { STGB(BL0, 2, kp0); STGB(BL0, 3, kp0); STGA(AL0, 1, kp0); STGA(AL0, 3, kp0); }
        if (pf) { PWAIT8; } else { PWAIT0; }
        MMA(1, b1v, 1);

        // ---- K-tile 2it+1 (buf1) ----
        LDA(Ab1, 0);
        LDB(b0v, Bb1, 0);
        PBAR;
        MMA(0, b0v, 0);
        LDB(b1v, Bb1, 1);
        if (pf) { STGA(AL1, 0, kp1); STGA(AL1, 2, kp1); }
        PBAR;
        MMA(0, b1v, 1);
        LDA(Ab1, 1);
        if (pf) { STGB(BL1, 0, kp1); STGB(BL1, 1, kp1); }
        PBAR;
        MMA(1, b0v, 0);
        if (pf) { STGB(BL1, 2, kp1); STGB(BL1, 3, kp1); STGA(AL1, 1, kp1); STGA(AL1, 3, kp1); }
        if (pf) { PWAIT8; } else { PWAIT0; }
        MMA(1, b1v, 1);
    }

#undef STGA
#undef STGB
#undef LDA
#undef LDB
#undef MMA

    // C/D layout 16x16x32 (m89/m91): col = lane&15, row = (lane>>4)*4 + reg
    float* Cb = C + (size_t)(moff + bm * 256 + (wm << 7) + (lane >> 4) * 4) * DDIM
                  + bn * 256 + (wn << 6) + l15;
#pragma unroll
    for (int fm = 0; fm < 8; ++fm)
#pragma unroll
        for (int fn = 0; fn < 4; ++fn)
#pragma unroll
            for (int r = 0; r < 4; ++r)
                Cb[(size_t)(fm * 16 + r) * DDIM + fn * 16] = acc[fm][fn][r];
}

extern "C" void kernel_launch(void* const* d_in, const int* in_sizes, int n_in,
                              void* d_out, int out_size, void* d_ws, size_t ws_size,
                              hipStream_t stream) {
    const float* X  = (const float*)d_in[0];  // (4,4096,2048)
    const float* W  = (const float*)d_in[1];  // (2048,2048)
    const float* G  = (const float*)d_in[2];  // gamma
    const float* Bt = (const float*)d_in[3];  // beta
    float* out = (float*)d_out;

    char* ws = (char*)d_ws;
    u16*   xq   = (u16*)ws;                                       // 67,108,864 B
    float* bufA = (float*)(ws + (size_t)67108864);                // 16,777,216 B
    float* bufB = (float*)(ws + (size_t)67108864 + 16777216);     // 16,777,216 B
    float* partial = bufB;        // 1024 floats, transient (consumed by colfwht<true>)
    u16*   w3      = (u16*)bufB;  // final bf16 weights, reuses bufB

    // w_scale partials
    absmean_part<<<1024, 256, 0, stream>>>((const float4*)W, partial);

    // w3 = H * ternary(W) * H via two column-FWHT passes (no transposes)
    {
        void (*k1)(const float*, void*, const float*) = colfwht<true, false>;
        void (*k2)(const float*, void*, const float*) = colfwht<false, true>;
        hipFuncSetAttribute(reinterpret_cast<const void*>(k1),
                            hipFuncAttributeMaxDynamicSharedMemorySize, DDIM * CFP * 4);
        hipFuncSetAttribute(reinterpret_cast<const void*>(k2),
                            hipFuncAttributeMaxDynamicSharedMemorySize, DDIM * CFP * 4);
        colfwht<true, false><<<256, 256, DDIM * CFP * 4, stream>>>(W, (void*)bufA, partial);
        colfwht<false, true><<<256, 256, DDIM * CFP * 4, stream>>>(bufA, (void*)w3, nullptr);
    }

    // activations
    ln_quant<<<MROWS, 256, 0, stream>>>(X, G, Bt, xq);

    // GEMM in two M-halves (diagnostic split; 256 blocks = 1/CU, m201-verified cfg)
    hipFuncSetAttribute(reinterpret_cast<const void*>(gemm256),
                        hipFuncAttributeMaxDynamicSharedMemorySize, 131072);
    gemm256<<<dim3(256), 512, 131072, stream>>>(xq, w3, out, 0);
    gemm256<<<dim3(256), 512, 131072, stream>>>(xq, w3, out, 8192);
}

// Round 6
// 374.930 us; speedup vs baseline: 1.0484x; 1.0484x over previous
//
#include <hip/hip_runtime.h>

typedef unsigned short u16;
typedef __attribute__((ext_vector_type(8))) __bf16 bf16x8;
typedef __attribute__((ext_vector_type(4))) float floatx4;

#define DDIM 2048
#define MROWS 16384   // 4*4096

__device__ __forceinline__ u16 f2bf(float f) {
    unsigned int u = __builtin_bit_cast(unsigned int, f);
    u = (u + 0x7fffu + ((u >> 16) & 1u)) >> 16;   // RNE
    return (u16)u;
}

__device__ __forceinline__ float wave_sum(float v) {
#pragma unroll
    for (int o = 32; o > 0; o >>= 1) v += __shfl_down(v, o, 64);
    return v;
}
__device__ __forceinline__ float wave_max(float v) {
#pragma unroll
    for (int o = 32; o > 0; o >>= 1) v = fmaxf(v, __shfl_down(v, o, 64));
    return v;
}

// ---------------- partial sums of |W| ----------------
__global__ __launch_bounds__(256) void absmean_part(const float4* __restrict__ W4,
                                                    float* __restrict__ partial) {
    float s = 0.f;
    for (int i = blockIdx.x * 256 + threadIdx.x; i < (DDIM * DDIM / 4); i += 1024 * 256) {
        float4 v = W4[i];
        s += fabsf(v.x) + fabsf(v.y) + fabsf(v.z) + fabsf(v.w);
    }
    s = wave_sum(s);
    __shared__ float red[4];
    if ((threadIdx.x & 63) == 0) red[threadIdx.x >> 6] = s;
    __syncthreads();
    if (threadIdx.x == 0) partial[blockIdx.x] = red[0] + red[1] + red[2] + red[3];
}

// ---------------- fused prep: {256 colfwht blocks || 4096 ln_quant blocks} -------
// colfwht (512 thr): column FWHT over the ROW index of a 2048x2048 matrix.
// Block b owns 8 columns; LDS slab S[2048][9] f32 (pitch 9 kills bank aliasing).
// QUANT: fuse w_scale finalize + ternary quantize (stage 1, reads W).
// BF16OUT: pack to bf16 (stage 2, writes w3). Result columns stored as output
// ROWS (coalesced) -> no transpose kernels needed.
// ln2 (512 thr): LayerNorm + int4 fake-quant for TWO rows (waves 0-3 row0,
// waves 4-7 row1; per-half reductions, no cross-half mixing).
#define CFP 9   // LDS pitch in floats

template <bool QUANT, bool BF16OUT>
__device__ __forceinline__ void colfwht512(const float* __restrict__ in,
                                           void* __restrict__ out,
                                           const float* __restrict__ partial,
                                           int blk, float* S) {
    const int t = threadIdx.x;
    const int c8 = blk * 8;

    float wsc = 0.f, half_t = 0.f;
    if (QUANT) {
        __shared__ float wred[8];
        float s = partial[t] + partial[t + 512];
        s = wave_sum(s);
        if ((t & 63) == 0) wred[t >> 6] = s;
        __syncthreads();
        float m = (wred[0] + wred[1] + wred[2] + wred[3] +
                   wred[4] + wred[5] + wred[6] + wred[7]) * (1.0f / (float)(DDIM * DDIM));
        wsc = fmaxf(m, 1e-6f);
        half_t = 0.5f * wsc;
    }

    // load (+quant): 4096 float4 per block; k = i*512+t; row = k>>1; half = k&1
#pragma unroll
    for (int i = 0; i < 8; ++i) {
        const int k = i * 512 + t;
        const int row = k >> 1, half = k & 1;
        float4 v = *(const float4*)(in + (size_t)row * DDIM + c8 + half * 4);
        if (QUANT) {
            v.x = (v.x > half_t ? wsc : 0.f) + (v.x < -half_t ? -wsc : 0.f);
            v.y = (v.y > half_t ? wsc : 0.f) + (v.y < -half_t ? -wsc : 0.f);
            v.z = (v.z > half_t ? wsc : 0.f) + (v.z < -half_t ? -wsc : 0.f);
            v.w = (v.w > half_t ? wsc : 0.f) + (v.w < -half_t ? -wsc : 0.f);
        }
        float* sp = S + row * CFP + half * 4;
        sp[0] = v.x; sp[1] = v.y; sp[2] = v.z; sp[3] = v.w;
    }
    __syncthreads();

    // 5 radix-4 stages: h = 1<<(2s)
#pragma unroll
    for (int s = 0; s < 5; ++s) {
        const int h = 1 << (2 * s);
#pragma unroll
        for (int i = 0; i < 8; ++i) {
            const int task = i * 512 + t;          // 4096 tasks = 512 quads x 8 cols
            const int p = task >> 3, c = task & 7;
            const int i0 = ((p >> (2 * s)) << (2 * s + 2)) | (p & (h - 1));
            float* a0 = S + (size_t)i0 * CFP + c;
            const float x0 = a0[0];
            const float x1 = a0[(size_t)h * CFP];
            const float x2 = a0[(size_t)2 * h * CFP];
            const float x3 = a0[(size_t)3 * h * CFP];
            const float s01 = x0 + x1, d01 = x0 - x1;
            const float s23 = x2 + x3, d23 = x2 - x3;
            a0[0]                   = s01 + s23;
            a0[(size_t)h * CFP]     = d01 + d23;
            a0[(size_t)2 * h * CFP] = s01 - s23;
            a0[(size_t)3 * h * CFP] = d01 - d23;
        }
        __syncthreads();
    }
    // final radix-2 stage: h = 1024
#pragma unroll
    for (int i = 0; i < 16; ++i) {
        const int task = i * 512 + t;              // 8192 tasks = 1024 pairs x 8 cols
        const int p = task >> 3, c = task & 7;
        float* a0 = S + (size_t)p * CFP + c;
        const float x0 = a0[0];
        const float x1 = a0[(size_t)1024 * CFP];
        a0[0] = x0 + x1;
        a0[(size_t)1024 * CFP] = x0 - x1;
    }
    __syncthreads();

    // store: column c of S -> output ROW (c8+c), coalesced
    const int c = t >> 6, l = t & 63;
#pragma unroll
    for (int i = 0; i < 8; ++i) {
        const int o4 = i * 64 + l;
        const float r0 = S[(size_t)(o4 * 4 + 0) * CFP + c];
        const float r1 = S[(size_t)(o4 * 4 + 1) * CFP + c];
        const float r2 = S[(size_t)(o4 * 4 + 2) * CFP + c];
        const float r3 = S[(size_t)(o4 * 4 + 3) * CFP + c];
        if (BF16OUT) {
            uint2 v;
            v.x = (unsigned)f2bf(r0) | ((unsigned)f2bf(r1) << 16);
            v.y = (unsigned)f2bf(r2) | ((unsigned)f2bf(r3) << 16);
            ((uint2*)((u16*)out + (size_t)(c8 + c) * DDIM))[o4] = v;
        } else {
            ((float4*)((float*)out + (size_t)(c8 + c) * DDIM))[o4] =
                make_float4(r0, r1, r2, r3);
        }
    }
}

__device__ __forceinline__ void ln2_block(const float* __restrict__ X,
                                          const float* __restrict__ G,
                                          const float* __restrict__ Bt,
                                          u16* __restrict__ XQ, int row0) {
    const int t = threadIdx.x;
    const int half = t >> 8, u = t & 255;   // half: which of the 2 rows
    const int row = row0 + half;
    const float4* rp = (const float4*)(X + (size_t)row * DDIM);
    float4 v0 = rp[u], v1 = rp[u + 256];
    float v[8] = {v0.x, v0.y, v0.z, v0.w, v1.x, v1.y, v1.z, v1.w};

    __shared__ float redA[8], redB[8], redC[8];
    const int wv = t >> 6, ln = t & 63;     // waves 0-3 = half0, 4-7 = half1
    const int b4 = half << 2;

    float s = 0.f, s2 = 0.f;
#pragma unroll
    for (int j = 0; j < 8; ++j) { s += v[j]; s2 += v[j] * v[j]; }
#pragma unroll
    for (int o = 32; o > 0; o >>= 1) {
        s += __shfl_down(s, o, 64);
        s2 += __shfl_down(s2, o, 64);
    }
    if (ln == 0) { redA[wv] = s; redB[wv] = s2; }
    __syncthreads();
    const float mu = (redA[b4] + redA[b4 + 1] + redA[b4 + 2] + redA[b4 + 3]) * (1.f / (float)DDIM);
    const float ex2 = (redB[b4] + redB[b4 + 1] + redB[b4 + 2] + redB[b4 + 3]) * (1.f / (float)DDIM);
    const float var = ex2 - mu * mu;
    const float rstd = rsqrtf(var + 1e-5f);

    const float4* gp = (const float4*)G;
    const float4* bp = (const float4*)Bt;
    float4 g0 = gp[u], g1 = gp[u + 256];
    float4 b0 = bp[u], b1 = bp[u + 256];
    float gg[8] = {g0.x, g0.y, g0.z, g0.w, g1.x, g1.y, g1.z, g1.w};
    float bb[8] = {b0.x, b0.y, b0.z, b0.w, b1.x, b1.y, b1.z, b1.w};

    float y[8];
    float am = 0.f;
#pragma unroll
    for (int j = 0; j < 8; ++j) {
        y[j] = (v[j] - mu) * rstd * gg[j] + bb[j];
        am = fmaxf(am, fabsf(y[j]));
    }
    float w = wave_max(am);
    if (ln == 0) redC[wv] = w;
    __syncthreads();
    const float scale = fmaxf(fmaxf(fmaxf(redC[b4], redC[b4 + 1]),
                                    fmaxf(redC[b4 + 2], redC[b4 + 3])), 1e-6f);

    const float r7 = 7.f / scale, s7 = scale / 7.f;
    unsigned int q[4];
#pragma unroll
    for (int j = 0; j < 8; j += 2) {
        float qa = fminf(fmaxf(rintf(y[j] * r7), -7.f), 7.f);
        float qb = fminf(fmaxf(rintf(y[j + 1] * r7), -7.f), 7.f);
        q[j >> 1] = (unsigned)f2bf(qa * s7) | ((unsigned)f2bf(qb * s7) << 16);
    }
    uint2 o0, o1;
    o0.x = q[0]; o0.y = q[1]; o1.x = q[2]; o1.y = q[3];
    uint2* orow = (uint2*)(XQ + (size_t)row * DDIM);
    orow[u] = o0;
    orow[u + 256] = o1;
}

template <bool QUANT, bool BF16OUT>
__global__ __launch_bounds__(512) void prep_fused(const float* __restrict__ win,
                                                  void* __restrict__ wout,
                                                  const float* __restrict__ partial,
                                                  const float* __restrict__ X,
                                                  const float* __restrict__ G,
                                                  const float* __restrict__ Bt,
                                                  u16* __restrict__ XQ,
                                                  int rowbase) {
    extern __shared__ float S[];   // 2048*CFP floats, used only by colfwht blocks
    if (blockIdx.x < 256) {
        colfwht512<QUANT, BF16OUT>(win, wout, partial, blockIdx.x, S);
    } else {
        ln2_block(X, G, Bt, XQ, rowbase + (int)(blockIdx.x - 256) * 2);
    }
}

// ---------------- GEMM: 256x256 tile, 8-phase, distributed staging ----------------
// Round-2 schedule (best measured: 117.2 us merged, MfmaUtil 52.9, 0 bank conflicts).
// C[16384][2048] = A[16384][2048] * B[2048(N)][2048(K)]^T, bf16 in / f32 out.
// 512 thr = 8 waves (2M x 4N); per-wave 128x64 output as 8x4 16x16x32 frags.
// Iteration = 2 K-tiles (even->buf0, odd->buf1), 8 phases, ONE barrier per phase.
// vmcnt(8) ONLY at ph4/ph8; issue->wait distance = 4 phases (~2000cy) -> no stall.
#define GBK 64
#define GNT (DDIM / GBK)      // 32 K-tiles
#define NITER (GNT / 2)       // 16 iterations
#define TILEU (256 * GBK)     // 16384 u16 per staged tile

__device__ __forceinline__ void gl_lds16(const u16* g, u16* l) {
    __builtin_amdgcn_global_load_lds((const __attribute__((address_space(1))) void*)g,
                                     (__attribute__((address_space(3))) void*)l,
                                     16, 0, 0);
}

#define PBAR do {                                                              \
    __builtin_amdgcn_sched_barrier(0);                                         \
    asm volatile("" ::: "memory");                                             \
    __builtin_amdgcn_s_barrier();                                              \
    asm volatile("" ::: "memory");                                             \
    __builtin_amdgcn_sched_barrier(0);                                         \
} while (0)

#define PWAIT8 do {                                                            \
    __builtin_amdgcn_sched_barrier(0);                                         \
    asm volatile("s_waitcnt vmcnt(8)" ::: "memory");                           \
    __builtin_amdgcn_s_barrier();                                              \
    asm volatile("" ::: "memory");                                             \
    __builtin_amdgcn_sched_barrier(0);                                         \
} while (0)

#define PWAIT0 do {                                                            \
    __builtin_amdgcn_sched_barrier(0);                                         \
    asm volatile("s_waitcnt vmcnt(0)" ::: "memory");                           \
    __builtin_amdgcn_s_barrier();                                              \
    asm volatile("" ::: "memory");                                             \
    __builtin_amdgcn_sched_barrier(0);                                         \
} while (0)

__global__ __launch_bounds__(512, 2) void gemm256(const u16* __restrict__ A,
                                                  const u16* __restrict__ B,
                                                  float* __restrict__ C) {
    extern __shared__ __align__(16) u16 lds[];   // 4 * TILEU u16 = 128 KiB
    const int t = threadIdx.x;
    const int lane = t & 63;
    const int wid = t >> 6;
    const int wm = wid >> 2;   // 0..1
    const int wn = wid & 3;    // 0..3

    // block mapping: 8 consecutive d share bm (A panel) on one XCD; bijective.
    const int d = blockIdx.x;
    const int bm = (d & 7) | ((d >> 6) << 3);   // 0..63
    const int bn = (d >> 3) & 7;                // 0..7

    const int l15 = lane & 15;
    const int kq = lane >> 4;
    const int x7 = lane & 7;
    const int c0 = (kq ^ x7) << 3;
    const int c1 = ((kq | 4) ^ x7) << 3;
    const int arow = (wm << 7) + l15;
    const int brow = (wn << 6) + l15;

    const int srow = t >> 3;
    const int gch = ((t & 7) ^ (srow & 7)) << 3;
    const u16* Ag = A + (size_t)(bm * 256 + srow) * DDIM + gch;
    const u16* Bg = B + (size_t)(bn * 256 + srow) * DDIM + gch;
    u16* const AL0 = lds + t * 8;
    u16* const BL0 = lds + TILEU + t * 8;
    u16* const AL1 = lds + 2 * TILEU + t * 8;
    u16* const BL1 = lds + 3 * TILEU + t * 8;
    const u16* const Ab0 = lds;
    const u16* const Bb0 = lds + TILEU;
    const u16* const Ab1 = lds + 2 * TILEU;
    const u16* const Bb1 = lds + 3 * TILEU;

    floatx4 acc[8][4];
#pragma unroll
    for (int i = 0; i < 8; ++i)
#pragma unroll
        for (int j = 0; j < 4; ++j)
#pragma unroll
            for (int e = 0; e < 4; ++e) acc[i][j][e] = 0.f;

    bf16x8 a[4][2], b0v[2][2], b1v[2][2];

#define STGA(dst, q, ko) gl_lds16(Ag + (size_t)((q) * 64) * DDIM + (ko), (dst) + (q) * 4096)
#define STGB(dst, q, ko) gl_lds16(Bg + (size_t)((q) * 64) * DDIM + (ko), (dst) + (q) * 4096)

#define LDA(Ab, mh)                                                            \
    _Pragma("unroll") for (int fm = 0; fm < 4; ++fm) {                         \
        const u16* p = (Ab) + (arow + (mh) * 64 + fm * 16) * GBK;              \
        a[fm][0] = *(const bf16x8*)(p + c0);                                   \
        a[fm][1] = *(const bf16x8*)(p + c1);                                   \
    }

#define LDB(dst, Bb, nh)                                                       \
    _Pragma("unroll") for (int fn = 0; fn < 2; ++fn) {                         \
        const u16* p = (Bb) + (brow + (nh) * 32 + fn * 16) * GBK;              \
        dst[fn][0] = *(const bf16x8*)(p + c0);                                 \
        dst[fn][1] = *(const bf16x8*)(p + c1);                                 \
    }

#define MMA(mh, bsrc, nh)                                                      \
    __builtin_amdgcn_s_setprio(1);                                             \
    _Pragma("unroll") for (int fm = 0; fm < 4; ++fm)                           \
        _Pragma("unroll") for (int fn = 0; fn < 2; ++fn)                       \
            _Pragma("unroll") for (int ks = 0; ks < 2; ++ks)                   \
                acc[(mh) * 4 + fm][(nh) * 2 + fn] =                            \
                    __builtin_amdgcn_mfma_f32_16x16x32_bf16(                   \
                        a[fm][ks], bsrc[fn][ks],                               \
                        acc[(mh) * 4 + fm][(nh) * 2 + fn], 0, 0, 0);           \
    __builtin_amdgcn_s_setprio(0);

#pragma unroll
    for (int q = 0; q < 4; ++q) STGA(AL0, q, 0);
#pragma unroll
    for (int q = 0; q < 4; ++q) STGB(BL0, q, 0);
#pragma unroll
    for (int q = 0; q < 4; ++q) STGA(AL1, q, GBK);
#pragma unroll
    for (int q = 0; q < 4; ++q) STGB(BL1, q, GBK);
    PWAIT8;

    for (int it = 0; it < NITER; ++it) {
        const int kp0 = (it * 2 + 2) * GBK;
        const int kp1 = kp0 + GBK;
        const bool pf = (it < NITER - 1);

        // ---- K-tile 2it (buf0) ----
        LDA(Ab0, 0);
        LDB(b0v, Bb0, 0);
        PBAR;
        MMA(0, b0v, 0);
        LDB(b1v, Bb0, 1);
        if (pf) { STGA(AL0, 0, kp0); STGA(AL0, 2, kp0); }
        PBAR;
        MMA(0, b1v, 1);
        LDA(Ab0, 1);
        if (pf) { STGB(BL0, 0, kp0); STGB(BL0, 1, kp0); }
        PBAR;
        MMA(1, b0v, 0);
        if (pf) { STGB(BL0, 2, kp0); STGB(BL0, 3, kp0); STGA(AL0, 1, kp0); STGA(AL0, 3, kp0); }
        if (pf) { PWAIT8; } else { PWAIT0; }
        MMA(1, b1v, 1);

        // ---- K-tile 2it+1 (buf1) ----
        LDA(Ab1, 0);
        LDB(b0v, Bb1, 0);
        PBAR;
        MMA(0, b0v, 0);
        LDB(b1v, Bb1, 1);
        if (pf) { STGA(AL1, 0, kp1); STGA(AL1, 2, kp1); }
        PBAR;
        MMA(0, b1v, 1);
        LDA(Ab1, 1);
        if (pf) { STGB(BL1, 0, kp1); STGB(BL1, 1, kp1); }
        PBAR;
        MMA(1, b0v, 0);
        if (pf) { STGB(BL1, 2, kp1); STGB(BL1, 3, kp1); STGA(AL1, 1, kp1); STGA(AL1, 3, kp1); }
        if (pf) { PWAIT8; } else { PWAIT0; }
        MMA(1, b1v, 1);
    }

#undef STGA
#undef STGB
#undef LDA
#undef LDB
#undef MMA

    // C/D layout 16x16x32 (m89/m91): col = lane&15, row = (lane>>4)*4 + reg
    float* Cb = C + (size_t)(bm * 256 + (wm << 7) + (lane >> 4) * 4) * DDIM
                  + bn * 256 + (wn << 6) + l15;
#pragma unroll
    for (int fm = 0; fm < 8; ++fm)
#pragma unroll
        for (int fn = 0; fn < 4; ++fn)
#pragma unroll
            for (int r = 0; r < 4; ++r)
                Cb[(size_t)(fm * 16 + r) * DDIM + fn * 16] = acc[fm][fn][r];
}

extern "C" void kernel_launch(void* const* d_in, const int* in_sizes, int n_in,
                              void* d_out, int out_size, void* d_ws, size_t ws_size,
                              hipStream_t stream) {
    const float* X  = (const float*)d_in[0];  // (4,4096,2048)
    const float* W  = (const float*)d_in[1];  // (2048,2048)
    const float* G  = (const float*)d_in[2];  // gamma
    const float* Bt = (const float*)d_in[3];  // beta
    float* out = (float*)d_out;

    char* ws = (char*)d_ws;
    u16*   xq   = (u16*)ws;                                       // 67,108,864 B
    float* bufA = (float*)(ws + (size_t)67108864);                // 16,777,216 B
    float* bufB = (float*)(ws + (size_t)67108864 + 16777216);     // 16,777,216 B
    float* partial = bufB;        // 1024 floats, consumed by prep_fused<true,...>
    u16*   w3      = (u16*)bufB;  // final bf16 weights, reuses bufB (written by K3
                                  // after K2 consumed partial)

    const int LDSZ = DDIM * CFP * 4;   // 73728 B

    // K1: w_scale partials
    absmean_part<<<1024, 256, 0, stream>>>((const float4*)W, partial);

    // K2: {colfwht stage1 (ternary quant, W->bufA)} || {ln_quant rows 0..8191}
    // K3: {colfwht stage2 (bufA->w3 bf16)}          || {ln_quant rows 8192..16383}
    {
        void (*k1)(const float*, void*, const float*, const float*, const float*,
                   const float*, u16*, int) = prep_fused<true, false>;
        void (*k2)(const float*, void*, const float*, const float*, const float*,
                   const float*, u16*, int) = prep_fused<false, true>;
        hipFuncSetAttribute(reinterpret_cast<const void*>(k1),
                            hipFuncAttributeMaxDynamicSharedMemorySize, LDSZ);
        hipFuncSetAttribute(reinterpret_cast<const void*>(k2),
                            hipFuncAttributeMaxDynamicSharedMemorySize, LDSZ);
        prep_fused<true, false><<<256 + 4096, 512, LDSZ, stream>>>(
            W, (void*)bufA, partial, X, G, Bt, xq, 0);
        prep_fused<false, true><<<256 + 4096, 512, LDSZ, stream>>>(
            bufA, (void*)w3, nullptr, X, G, Bt, xq, 8192);
    }

    // K4: GEMM (merged, round-2 8-phase distributed-stage pipeline, 128 KiB LDS)
    hipFuncSetAttribute(reinterpret_cast<const void*>(gemm256),
                        hipFuncAttributeMaxDynamicSharedMemorySize, 131072);
    gemm256<<<dim3(512), 512, 131072, stream>>>(xq, w3, out);
}